// Round 2
// baseline (361.006 us; speedup 1.0000x reference)
//
#include <hip/hip_runtime.h>

// N=100000 nodes, M=800000 edges, F_IN=64, F_E=16, H=64, T_NODE=2, T_EDGE=3.
// score == softmax over singleton axis == 1.0 exactly, so h3/h4/num are dead:
//   out[n] = h1[n] + sum_{e: dst=n} ( h2[src_e] + ef_e . W5[t_e] + b5[t_e] )
//
// R9: K1 unchanged. K2 restructured to be LDS-free:
//  - each gather wave owns G=8 consecutive dsts; the 51x64 [W5;b5] is held
//    as 51 per-lane registers (Wcol[j] = column `lane`), loaded once per wave
//    from L2 (12 KB hot set).
//  - per-dst matvec = 51 x (v_readlane(accS) + fma) on 3 parallel chains.
//    No ds_read at all (R8 lesson: the LDS epilogue was the bottleneck and
//    transposing it created 8-way bank conflicts).
//  - one-deep prefetch of next dst's cnt + first-8 rec slots; prefetched rec
//    may be stale past deg, so lane addresses are cndmask'd to 0 before use.

#define CAP 16
#define OVF_CAP 32768
#define GPW 8   // dsts per gather wave

typedef __attribute__((ext_vector_type(8))) short short8;
typedef __attribute__((ext_vector_type(4))) float f32x4;

__device__ __forceinline__ float b2f(unsigned short u) {
    union { unsigned v; float f; } x; x.v = ((unsigned)u) << 16; return x.f;
}
__device__ __forceinline__ unsigned short f2b(float f) {
    union { float f; unsigned v; } x; x.f = f;
    unsigned u = x.v;
    unsigned r = (u + 0x7FFFu + ((u >> 16) & 1u)) >> 16;
    return (unsigned short)r;
}
__device__ __forceinline__ float rl(float v, int j) {
    union { float f; int i; } a, b;
    a.f = v;
    b.i = __builtin_amdgcn_readlane(a.i, j);
    return b.f;
}

// ---------------- K1: gemm (even blocks) || slot scatter (odd blocks) -------
__global__ __launch_bounds__(256) void k1_gemm_scatter(
    const float* __restrict__ x, const int* __restrict__ nt,
    const float* __restrict__ W1, const float* __restrict__ b1,
    const float* __restrict__ W2, const float* __restrict__ b2,
    const int* __restrict__ esrc, const int* __restrict__ edst,
    const int* __restrict__ etype,
    int* __restrict__ cnt32, int* __restrict__ ovfCnt,
    int4* __restrict__ ovf, int2* __restrict__ rec,
    float* __restrict__ out, unsigned short* __restrict__ h2b,
    int N, int M)
{
    // 72 = 64 + 8 pad: row stride 144 B -> 2-way bank alias (free)
    __shared__ __align__(16) unsigned short sx[128 * 72];     // 18 KB
    __shared__ __align__(16) unsigned short sw[4][64 * 72];   // 36 KB
    __shared__ int snt[128];

    int tid = threadIdx.x;

    if (blockIdx.x & 1) {
        // ---------------- scatter path: 1024 edges/block, 4 per thread ------
        int e0 = (blockIdx.x >> 1) * 1024 + tid;
        int dd[4], ssrc[4], tty[4];
        bool v[4];
#pragma unroll
        for (int j = 0; j < 4; ++j) {
            int e = e0 + j * 256;
            v[j] = e < M;
            int ec = v[j] ? e : 0;
            dd[j]   = edst[ec];
            ssrc[j] = esrc[ec];
            tty[j]  = etype[ec];
        }
        int pos[4];
#pragma unroll
        for (int j = 0; j < 4; ++j)
            if (v[j]) pos[j] = atomicAdd(&cnt32[dd[j]], 1);
#pragma unroll
        for (int j = 0; j < 4; ++j) {
            if (!v[j]) continue;
            int packed = ssrc[j] | (tty[j] << 20);
            int e = e0 + j * 256;
            if (pos[j] < CAP) {
                rec[dd[j] * CAP + pos[j]] = make_int2(packed, e);
            } else {
                int slot = atomicAdd(ovfCnt, 1);
                if (slot < OVF_CAP) ovf[slot] = make_int4(packed, e, dd[j], 0);
            }
        }
        return;
    }

    // ---------------- gemm path: 128 rows x 64 h, 4 weight mats -------------
    int rowbase = (blockIdx.x >> 1) * 128;

    const float* Wm0 = W1;            // [k][n] fp32, type 0
    const float* Wm1 = W1 + 4096;     // type 1
    const float* Wm2 = W2;
    const float* Wm3 = W2 + 4096;
#pragma unroll
    for (int j = 0; j < 4; ++j) {
        int k  = (tid >> 4) + j * 16;
        int n4 = (tid & 15) * 4;
        float4 w0 = *(const float4*)&Wm0[k * 64 + n4];
        float4 w1v = *(const float4*)&Wm1[k * 64 + n4];
        float4 w2v = *(const float4*)&Wm2[k * 64 + n4];
        float4 w3 = *(const float4*)&Wm3[k * 64 + n4];
        sw[0][(n4 + 0) * 72 + k] = f2b(w0.x);
        sw[0][(n4 + 1) * 72 + k] = f2b(w0.y);
        sw[0][(n4 + 2) * 72 + k] = f2b(w0.z);
        sw[0][(n4 + 3) * 72 + k] = f2b(w0.w);
        sw[1][(n4 + 0) * 72 + k] = f2b(w1v.x);
        sw[1][(n4 + 1) * 72 + k] = f2b(w1v.y);
        sw[1][(n4 + 2) * 72 + k] = f2b(w1v.z);
        sw[1][(n4 + 3) * 72 + k] = f2b(w1v.w);
        sw[2][(n4 + 0) * 72 + k] = f2b(w2v.x);
        sw[2][(n4 + 1) * 72 + k] = f2b(w2v.y);
        sw[2][(n4 + 2) * 72 + k] = f2b(w2v.z);
        sw[2][(n4 + 3) * 72 + k] = f2b(w2v.w);
        sw[3][(n4 + 0) * 72 + k] = f2b(w3.x);
        sw[3][(n4 + 1) * 72 + k] = f2b(w3.y);
        sw[3][(n4 + 2) * 72 + k] = f2b(w3.z);
        sw[3][(n4 + 3) * 72 + k] = f2b(w3.w);
    }

    if (tid < 128) {
        int r = rowbase + tid;
        snt[tid] = (r < N) ? nt[r] : 0;
    }

    // stage x tile (contiguous rows, no perm)
    int fr = (tid & 15) * 4;
    int ir = tid >> 4;
#pragma unroll
    for (int it = 0; it < 8; ++it) {
        int i = it * 16 + ir;
        int r = rowbase + i;
        float4 v = make_float4(0.f, 0.f, 0.f, 0.f);
        if (r < N) v = *(const float4*)&x[(size_t)r * 64 + fr];
        ushort4 p;
        p.x = f2b(v.x); p.y = f2b(v.y); p.z = f2b(v.z); p.w = f2b(v.w);
        *(ushort4*)&sx[i * 72 + fr] = p;
    }
    __syncthreads();

    int lane = tid & 63;
    int wid  = tid >> 6;
    int q    = lane >> 4;
    int cc   = lane & 15;
    int m0   = wid * 32;

    f32x4 acc[4][2][4];   // [mat][s][t]
#pragma unroll
    for (int mm = 0; mm < 4; ++mm)
#pragma unroll
        for (int s = 0; s < 2; ++s)
#pragma unroll
            for (int t = 0; t < 4; ++t)
                acc[mm][s][t] = (f32x4){0.f, 0.f, 0.f, 0.f};

#pragma unroll
    for (int k0 = 0; k0 < 64; k0 += 32) {
        int ko = k0 + q * 8;
        short8 af0 = *(short8*)&sx[(m0 + cc) * 72 + ko];
        short8 af1 = *(short8*)&sx[(m0 + 16 + cc) * 72 + ko];
#pragma unroll
        for (int mm = 0; mm < 4; ++mm)
#pragma unroll
            for (int t = 0; t < 4; ++t) {
                short8 bf = *(short8*)&sw[mm][(t * 16 + cc) * 72 + ko];
                acc[mm][0][t] = __builtin_amdgcn_mfma_f32_16x16x32_bf16(
                    af0, bf, acc[mm][0][t], 0, 0, 0);
                acc[mm][1][t] = __builtin_amdgcn_mfma_f32_16x16x32_bf16(
                    af1, bf, acc[mm][1][t], 0, 0, 0);
            }
    }

    float b1v[2][4], b2v[2][4];
#pragma unroll
    for (int ty = 0; ty < 2; ++ty)
#pragma unroll
        for (int t = 0; t < 4; ++t) {
            b1v[ty][t] = b1[ty * 64 + t * 16 + cc];
            b2v[ty][t] = b2[ty * 64 + t * 16 + cc];
        }

    // C/D layout: col = lane&15, row = quad*4 + reg
#pragma unroll
    for (int s = 0; s < 2; ++s)
#pragma unroll
        for (int reg = 0; reg < 4; ++reg) {
            int rl_ = m0 + s * 16 + q * 4 + reg;
            int r = rowbase + rl_;
            if (r < N) {
                int ty = snt[rl_];
#pragma unroll
                for (int t = 0; t < 4; ++t) {
                    float v1 = (ty ? acc[1][s][t][reg] : acc[0][s][t][reg])
                               + b1v[ty][t];
                    float v2 = (ty ? acc[3][s][t][reg] : acc[2][s][t][reg])
                               + b2v[ty][t];
                    out[(size_t)r * 64 + t * 16 + cc] = v1;
                    h2b[(size_t)r * 64 + t * 16 + cc] = f2b(v2);
                }
            }
        }
}

// ---------------- K2: LDS-free gather, G dsts per wave ----------------------
// lane roles in edge loop: all lanes accH += h2b[src][lane];
//   lanes 0..47: accS += (etype == lane>>4) ? ef[edge][lane&15] : 0
//   lanes 48..50: accS += (etype == lane-48) ? 1 : 0
// epilogue per dst: out[d][lane] += accH + sum_j readlane(accS,j)*Wcol[j]
// with Wcol[j] = [W5;b5][j][lane] resident in 51 VGPRs (loaded once/wave).
__global__ __launch_bounds__(256, 3) void k2_gather(
    const float* __restrict__ ef, const int2* __restrict__ rec,
    const int* __restrict__ cnt32,
    const float* __restrict__ W5, const float* __restrict__ b5,
    const int4* __restrict__ ovf, const int* __restrict__ ovfCnt,
    const unsigned short* __restrict__ h2b, float* __restrict__ out,
    int N, int gatherBlocks, int ovfBlocks)
{
    int tid = threadIdx.x;
    int lane = tid & 63;
    int wid = tid >> 6;

    if (blockIdx.x >= (unsigned)gatherBlocks) {
        // ---- overflow fixup: grid-stride waves over ovf list (rare) ----
        int novf = min(*ovfCnt, OVF_CAP);
        int gw = (blockIdx.x - gatherBlocks) * 4 + wid;
        int nw = ovfBlocks * 4;
        for (int ri = gw; ri < novf; ri += nw) {
            int4 o = ovf[ri];
            int s = o.x & 0xFFFFF;
            int t = (unsigned)o.x >> 20;
            float acc = b5[t * 64 + lane] + b2f(h2b[((size_t)s << 6) | lane]);
#pragma unroll
            for (int f = 0; f < 16; ++f)
                acc = fmaf(ef[(size_t)o.y * 16 + f],
                           W5[(t * 16 + f) * 64 + lane], acc);
            unsafeAtomicAdd(&out[(size_t)o.z * 64 + lane], acc);
        }
        return;
    }

    // weights into registers: Wcol[j] = [W5;b5] row j, column `lane`
    float Wcol[51];
#pragma unroll
    for (int j = 0; j < 48; ++j) Wcol[j] = W5[j * 64 + lane];
#pragma unroll
    for (int t = 0; t < 3; ++t) Wcol[48 + t] = b5[t * 64 + lane];

    int base_d = (blockIdx.x * 4 + wid) * GPW;
    int myt = (lane < 48) ? (lane >> 4) : (lane - 48);
    unsigned myf = lane & 15;
    bool fl = lane < 48;

    // prefetch dst 0: count + first 8 record slots (values may be stale
    // past deg -- never used to form addresses without masking)
    int degC = 0;
    int2 rC[8];
    if (base_d < N) {
        degC = cnt32[base_d];
        unsigned rb = (unsigned)base_d * CAP;
#pragma unroll
        for (int j = 0; j < 8; ++j) rC[j] = rec[rb + j];
    }

#pragma unroll 1
    for (int g = 0; g < GPW; ++g) {
        int d = base_d + g;
        // prefetch next dst
        int dn = d + 1;
        int degN = 0;
        int2 rN[8];
        if (g + 1 < GPW && dn < N) {
            degN = cnt32[dn];
            unsigned rb = (unsigned)dn * CAP;
#pragma unroll
            for (int j = 0; j < 8; ++j) rN[j] = rec[rb + j];
        }

        if (d < N) {
            int dg = min(degC, CAP);
            if (dg > 0) {
                float accH = 0.f, accS = 0.f;
                // chunk 0: prefetched records, mask lanes past dg
#pragma unroll
                for (int j = 0; j < 8; ++j) {
                    bool ok = j < dg;
                    int px = ok ? rC[j].x : 0;   // safe address when stale
                    int py = ok ? rC[j].y : 0;
                    unsigned s = (unsigned)px & 0xFFFFFu;
                    float hv = b2f(h2b[((size_t)s << 6) | (unsigned)lane]);
                    float evv = ef[((unsigned)py << 4) | myf];
                    int t = (int)((unsigned)px >> 20);
                    accH += ok ? hv : 0.f;
                    float v = fl ? evv : 1.0f;
                    accS += (ok && t == myt) ? v : 0.f;
                }
                // chunk 1 (deg > 8): clamped on-demand loads (always valid)
                if (dg > 8) {
                    int dgm1 = dg - 1;
                    unsigned rb = (unsigned)d * CAP;
                    int2 r2[8];
#pragma unroll
                    for (int j = 0; j < 8; ++j)
                        r2[j] = rec[rb + (unsigned)min(8 + j, dgm1)];
#pragma unroll
                    for (int j = 0; j < 8; ++j) {
                        unsigned s = (unsigned)r2[j].x & 0xFFFFFu;
                        float hv = b2f(h2b[((size_t)s << 6) | (unsigned)lane]);
                        float evv = ef[((unsigned)r2[j].y << 4) | myf];
                        int t = (int)((unsigned)r2[j].x >> 20);
                        bool ok = (8 + j) < dg;
                        accH += ok ? hv : 0.f;
                        float v = fl ? evv : 1.0f;
                        accS += (ok && t == myt) ? v : 0.f;
                    }
                }
                // epilogue: 51-step broadcast-matvec, 3 parallel fma chains
                float rr0 = accH, rr1 = 0.f, rr2 = 0.f;
#pragma unroll
                for (int j = 0; j < 17; ++j) {
                    rr0 = fmaf(rl(accS, 3 * j + 0), Wcol[3 * j + 0], rr0);
                    rr1 = fmaf(rl(accS, 3 * j + 1), Wcol[3 * j + 1], rr1);
                    rr2 = fmaf(rl(accS, 3 * j + 2), Wcol[3 * j + 2], rr2);
                }
                float rr = rr0 + (rr1 + rr2);
                unsafeAtomicAdd(&out[((size_t)(unsigned)d << 6) | lane], rr);
            }
        }

        degC = degN;
#pragma unroll
        for (int j = 0; j < 8; ++j) rC[j] = rN[j];
    }
}

extern "C" void kernel_launch(void* const* d_in, const int* in_sizes, int n_in,
                              void* d_out, int out_size, void* d_ws, size_t ws_size,
                              hipStream_t stream) {
    const float* x  = (const float*)d_in[0];
    const float* ef = (const float*)d_in[1];
    const int* nt   = (const int*)d_in[2];
    const int* es   = (const int*)d_in[3];
    const int* ed   = (const int*)d_in[4];
    const int* et   = (const int*)d_in[5];
    const float* W1 = (const float*)d_in[6];
    const float* b1 = (const float*)d_in[7];
    const float* W2 = (const float*)d_in[8];
    const float* b2 = (const float*)d_in[9];
    // d_in[10..13] = W3,b3,W4,b4 dead (score == 1.0)
    const float* W5 = (const float*)d_in[14];
    const float* b5 = (const float*)d_in[15];

    int N = in_sizes[2];
    int M = in_sizes[3];

    char* w = (char*)d_ws;
    size_t off = 0;
    unsigned short* h2b = (unsigned short*)(w + off); off += (size_t)N * 64 * 2;  // 12.8 MB
    off = (off + 255) & ~(size_t)255;
    int2* rec = (int2*)(w + off); off += (size_t)N * CAP * 8;                     // 12.8 MB
    off = (off + 255) & ~(size_t)255;
    int4* ovf = (int4*)(w + off); off += (size_t)OVF_CAP * 16;                    // 0.5 MB
    off = (off + 255) & ~(size_t)255;
    // zero block: [ovfCnt:1 int][pad->64 B][cnt32: N ints]
    int* ovfCnt = (int*)(w + off);
    int* cnt32  = (int*)(w + off + 64);
    size_t zeroBytes = 64 + (size_t)N * 4;

    float* out = (float*)d_out;

    hipMemsetAsync(ovfCnt, 0, zeroBytes, stream);

    int gemmBlocks    = (N + 127) / 128;    // 782
    int scatterBlocks = (M + 1023) / 1024;  // 782
    int gb1 = 2 * max(gemmBlocks, scatterBlocks);
    k1_gemm_scatter<<<gb1, 256, 0, stream>>>(
        x, nt, W1, b1, W2, b2, es, ed, et,
        cnt32, ovfCnt, ovf, rec, out, h2b, N, M);

    int gatherBlocks = (N + 4 * GPW - 1) / (4 * GPW);   // 3125
    int ovfBlocks = 32;
    k2_gather<<<gatherBlocks + ovfBlocks, 256, 0, stream>>>(
        ef, rec, cnt32, W5, b5, ovf, ovfCnt, h2b, out,
        N, gatherBlocks, ovfBlocks);
}

// Round 7
// 314.278 us; speedup vs baseline: 1.1487x; 1.1487x over previous
//
#include <hip/hip_runtime.h>

// N=100000 nodes, M=800000 edges, F_IN=64, F_E=16, H=64, T_NODE=2, T_EDGE=3.
// score == softmax over singleton axis == 1.0 exactly, so h3/h4/num are dead:
//   out[n] = h1[n] + sum_{e: dst=n} ( h2[src_e] + ef_e . W5[t_e] + b5[t_e] )
//
// R14: real NaN fix. R10/R13's K3 tail-zeroing only covered K-cols 104..115
// (used sp=(idx%3)*4 -> 3 ushort4 = 12 cols, but the tail is 24 cols wide).
// Cols 116..127 of BOTH LDS tiles were uninitialized; MFMA reads full [0,128)
// -> garbage x garbage = NaN. Now: A-tail 128rows x 6 ushort4 = 768 tasks,
// B-tail 64rows x 6 ushort4 = 384 tasks, full [104,128) coverage.
//  K1: parity-interleaved MFMA node gemm / slot scatter (unchanged, proven).
//  K2: LDS-free gather; per dst accumulates accH (h2 row sum) + accS
//      (51-vector), stores accS to sacc[N x 52], atomic-adds accH to out.
//  K3: out += sacc * [W5;b5] via MFMA (hi/lo bf16 split, K=128).

#define CAP 16
#define OVF_CAP 32768

typedef __attribute__((ext_vector_type(8))) short short8;
typedef __attribute__((ext_vector_type(4))) float f32x4;

__device__ __forceinline__ float b2f(unsigned short u) {
    union { unsigned v; float f; } x; x.v = ((unsigned)u) << 16; return x.f;
}
__device__ __forceinline__ unsigned short f2b(float f) {
    union { float f; unsigned v; } x; x.f = f;
    unsigned u = x.v;
    unsigned r = (u + 0x7FFFu + ((u >> 16) & 1u)) >> 16;
    return (unsigned short)r;
}

// ---------------- K1: gemm (even blocks) || slot scatter (odd blocks) -------
__global__ __launch_bounds__(256) void k1_gemm_scatter(
    const float* __restrict__ x, const int* __restrict__ nt,
    const float* __restrict__ W1, const float* __restrict__ b1,
    const float* __restrict__ W2, const float* __restrict__ b2,
    const int* __restrict__ esrc, const int* __restrict__ edst,
    const int* __restrict__ etype,
    int* __restrict__ cnt32, int* __restrict__ ovfCnt,
    int4* __restrict__ ovf, int2* __restrict__ rec,
    float* __restrict__ out, unsigned short* __restrict__ h2b,
    int N, int M)
{
    // 72 = 64 + 8 pad: row stride 144 B -> 2-way bank alias (free)
    __shared__ __align__(16) unsigned short sx[128 * 72];     // 18 KB
    __shared__ __align__(16) unsigned short sw[4][64 * 72];   // 36 KB
    __shared__ int snt[128];

    int tid = threadIdx.x;

    if (blockIdx.x & 1) {
        // ---------------- scatter path: 1024 edges/block, 4 per thread ------
        int e0 = (blockIdx.x >> 1) * 1024 + tid;
        int dd[4], ssrc[4], tty[4];
        bool v[4];
#pragma unroll
        for (int j = 0; j < 4; ++j) {
            int e = e0 + j * 256;
            v[j] = e < M;
            int ec = v[j] ? e : 0;
            dd[j]   = edst[ec];
            ssrc[j] = esrc[ec];
            tty[j]  = etype[ec];
        }
        int pos[4];
#pragma unroll
        for (int j = 0; j < 4; ++j)
            if (v[j]) pos[j] = atomicAdd(&cnt32[dd[j]], 1);
#pragma unroll
        for (int j = 0; j < 4; ++j) {
            if (!v[j]) continue;
            int packed = ssrc[j] | (tty[j] << 20);
            int e = e0 + j * 256;
            if (pos[j] < CAP) {
                rec[dd[j] * CAP + pos[j]] = make_int2(packed, e);
            } else {
                int slot = atomicAdd(ovfCnt, 1);
                if (slot < OVF_CAP) ovf[slot] = make_int4(packed, e, dd[j], 0);
            }
        }
        return;
    }

    // ---------------- gemm path: 128 rows x 64 h, 4 weight mats -------------
    int rowbase = (blockIdx.x >> 1) * 128;

    const float* Wm0 = W1;            // [k][n] fp32, type 0
    const float* Wm1 = W1 + 4096;     // type 1
    const float* Wm2 = W2;
    const float* Wm3 = W2 + 4096;
#pragma unroll
    for (int j = 0; j < 4; ++j) {
        int k  = (tid >> 4) + j * 16;
        int n4 = (tid & 15) * 4;
        float4 w0 = *(const float4*)&Wm0[k * 64 + n4];
        float4 w1v = *(const float4*)&Wm1[k * 64 + n4];
        float4 w2v = *(const float4*)&Wm2[k * 64 + n4];
        float4 w3 = *(const float4*)&Wm3[k * 64 + n4];
        sw[0][(n4 + 0) * 72 + k] = f2b(w0.x);
        sw[0][(n4 + 1) * 72 + k] = f2b(w0.y);
        sw[0][(n4 + 2) * 72 + k] = f2b(w0.z);
        sw[0][(n4 + 3) * 72 + k] = f2b(w0.w);
        sw[1][(n4 + 0) * 72 + k] = f2b(w1v.x);
        sw[1][(n4 + 1) * 72 + k] = f2b(w1v.y);
        sw[1][(n4 + 2) * 72 + k] = f2b(w1v.z);
        sw[1][(n4 + 3) * 72 + k] = f2b(w1v.w);
        sw[2][(n4 + 0) * 72 + k] = f2b(w2v.x);
        sw[2][(n4 + 1) * 72 + k] = f2b(w2v.y);
        sw[2][(n4 + 2) * 72 + k] = f2b(w2v.z);
        sw[2][(n4 + 3) * 72 + k] = f2b(w2v.w);
        sw[3][(n4 + 0) * 72 + k] = f2b(w3.x);
        sw[3][(n4 + 1) * 72 + k] = f2b(w3.y);
        sw[3][(n4 + 2) * 72 + k] = f2b(w3.z);
        sw[3][(n4 + 3) * 72 + k] = f2b(w3.w);
    }

    if (tid < 128) {
        int r = rowbase + tid;
        snt[tid] = (r < N) ? nt[r] : 0;
    }

    // stage x tile (contiguous rows, no perm)
    int fr = (tid & 15) * 4;
    int ir = tid >> 4;
#pragma unroll
    for (int it = 0; it < 8; ++it) {
        int i = it * 16 + ir;
        int r = rowbase + i;
        float4 v = make_float4(0.f, 0.f, 0.f, 0.f);
        if (r < N) v = *(const float4*)&x[(size_t)r * 64 + fr];
        ushort4 p;
        p.x = f2b(v.x); p.y = f2b(v.y); p.z = f2b(v.z); p.w = f2b(v.w);
        *(ushort4*)&sx[i * 72 + fr] = p;
    }
    __syncthreads();

    int lane = tid & 63;
    int wid  = tid >> 6;
    int q    = lane >> 4;
    int cc   = lane & 15;
    int m0   = wid * 32;

    f32x4 acc[4][2][4];   // [mat][s][t]
#pragma unroll
    for (int mm = 0; mm < 4; ++mm)
#pragma unroll
        for (int s = 0; s < 2; ++s)
#pragma unroll
            for (int t = 0; t < 4; ++t)
                acc[mm][s][t] = (f32x4){0.f, 0.f, 0.f, 0.f};

#pragma unroll
    for (int k0 = 0; k0 < 64; k0 += 32) {
        int ko = k0 + q * 8;
        short8 af0 = *(short8*)&sx[(m0 + cc) * 72 + ko];
        short8 af1 = *(short8*)&sx[(m0 + 16 + cc) * 72 + ko];
#pragma unroll
        for (int mm = 0; mm < 4; ++mm)
#pragma unroll
            for (int t = 0; t < 4; ++t) {
                short8 bf = *(short8*)&sw[mm][(t * 16 + cc) * 72 + ko];
                acc[mm][0][t] = __builtin_amdgcn_mfma_f32_16x16x32_bf16(
                    af0, bf, acc[mm][0][t], 0, 0, 0);
                acc[mm][1][t] = __builtin_amdgcn_mfma_f32_16x16x32_bf16(
                    af1, bf, acc[mm][1][t], 0, 0, 0);
            }
    }

    float b1v[2][4], b2v[2][4];
#pragma unroll
    for (int ty = 0; ty < 2; ++ty)
#pragma unroll
        for (int t = 0; t < 4; ++t) {
            b1v[ty][t] = b1[ty * 64 + t * 16 + cc];
            b2v[ty][t] = b2[ty * 64 + t * 16 + cc];
        }

    // C/D layout: col = lane&15, row = quad*4 + reg
#pragma unroll
    for (int s = 0; s < 2; ++s)
#pragma unroll
        for (int reg = 0; reg < 4; ++reg) {
            int rl_ = m0 + s * 16 + q * 4 + reg;
            int r = rowbase + rl_;
            if (r < N) {
                int ty = snt[rl_];
#pragma unroll
                for (int t = 0; t < 4; ++t) {
                    float v1 = (ty ? acc[1][s][t][reg] : acc[0][s][t][reg])
                               + b1v[ty][t];
                    float v2 = (ty ? acc[3][s][t][reg] : acc[2][s][t][reg])
                               + b2v[ty][t];
                    out[(size_t)r * 64 + t * 16 + cc] = v1;
                    h2b[(size_t)r * 64 + t * 16 + cc] = f2b(v2);
                }
            }
        }
}

// ---------------- K2: LDS-free gather (one wave per dst) --------------------
// lane roles: all lanes accH += h2b[src][lane];
//   lanes 0..47: accS += (etype == lane>>4) ? ef[edge][lane&15] : 0
//   lanes 48..50: accS += (etype == lane-48) ? 1 : 0   (lanes>=51 stay 0)
// ends: sacc[d][lane] = accS (lane<52), out[d] += accH (atomic).
__global__ __launch_bounds__(256) void k2_gather(
    const float* __restrict__ ef, const int2* __restrict__ rec,
    const int* __restrict__ cnt32,
    const float* __restrict__ W5, const float* __restrict__ b5,
    const int4* __restrict__ ovf, const int* __restrict__ ovfCnt,
    const unsigned short* __restrict__ h2b, float* __restrict__ out,
    float* __restrict__ sacc,
    int N, int gatherBlocks, int ovfBlocks)
{
    int tid = threadIdx.x;
    int lane = tid & 63;
    int wid = tid >> 6;

    if (blockIdx.x >= (unsigned)gatherBlocks) {
        // ---- overflow fixup: grid-stride waves over ovf list (rare) ----
        int novf = min(*ovfCnt, OVF_CAP);
        int gw = (blockIdx.x - gatherBlocks) * 4 + wid;
        int nw = ovfBlocks * 4;
        for (int ri = gw; ri < novf; ri += nw) {
            int4 o = ovf[ri];
            int s = o.x & 0xFFFFF;
            int t = (unsigned)o.x >> 20;
            float acc = b5[t * 64 + lane] + b2f(h2b[((size_t)s << 6) | lane]);
#pragma unroll
            for (int f = 0; f < 16; ++f)
                acc = fmaf(ef[(size_t)o.y * 16 + f],
                           W5[(t * 16 + f) * 64 + lane], acc);
            unsafeAtomicAdd(&out[(size_t)o.z * 64 + lane], acc);
        }
        return;
    }

    int d = blockIdx.x * 4 + wid;
    if (d >= N) return;

    int dg = min(cnt32[d], CAP);
    unsigned base = (unsigned)d * CAP;

    int myt = (lane < 48) ? (lane >> 4) : (lane - 48);
    unsigned myf = lane & 15;
    bool fl = lane < 48;
    float accH = 0.f, accS = 0.f;
    float hLast = 0.f, vLast = 0.f;
    int tLast = -1;
    int dgm1 = dg - 1;

    for (int i = 0; i < dg; i += 8) {
        int2 r[8];
#pragma unroll
        for (int j = 0; j < 8; ++j) {
            int ij = min(i + j, dgm1);            // clamp to written slots
            r[j] = rec[base + ij];
        }
        float hv[8], ev[8];
#pragma unroll
        for (int j = 0; j < 8; ++j) {
            unsigned s = (unsigned)r[j].x & 0xFFFFFu;
            hv[j] = b2f(h2b[((size_t)s << 6) | (unsigned)lane]);
            ev[j] = ef[((unsigned)r[j].y << 4) | myf];
        }
#pragma unroll
        for (int j = 0; j < 8; ++j) {
            int t = (int)((unsigned)r[j].x >> 20);
            float v = fl ? ev[j] : 1.0f;
            accH += hv[j];
            accS += (t == myt) ? v : 0.f;
            hLast = hv[j]; vLast = v; tLast = t;  // dead except final j
        }
    }
    // slots past dg re-read record dg-1: subtract the duplicates once
    float fd = (float)(((dg + 7) & ~7) - dg);
    accH -= fd * hLast;
    accS -= (tLast == myt) ? fd * vLast : 0.f;

    if (lane < 52)
        sacc[(size_t)d * 52 + lane] = accS;       // lane 51 writes exact 0
    if (dg > 0)
        unsafeAtomicAdd(&out[((size_t)(unsigned)d << 6) | lane], accH);
}

// ---------------- K3: out += sacc[N x 52] * [W5;b5]  (MFMA) -----------------
// A tile [128 rows x 128 K] bf16: cols 0..51 = hi(accS), 52..103 = lo(accS),
// 104..127 = 0. B tile [128 K x 64 h]: rows 0..50 = [W5;b5], 52..102 = same,
// rows 51/103 and 104..127 = 0. K=128 loop computes hi*W + lo*W.
__global__ __launch_bounds__(256) void k3_sacc_gemm(
    const float* __restrict__ sacc, const float* __restrict__ W5,
    const float* __restrict__ b5, float* __restrict__ out, int N)
{
    __shared__ __align__(16) unsigned short sa[128 * 136];   // 34 KB
    __shared__ __align__(16) unsigned short swt[64 * 136];   // 17 KB

    int tid = threadIdx.x;
    int rowbase = blockIdx.x * 128;

    // ---- stage A: 128 rows x 13 float4 = 1664 tasks ----
#pragma unroll
    for (int k = 0; k < 7; ++k) {
        int idx = tid + k * 256;
        if (idx < 1664) {
            int row = idx / 13;
            int q4 = (idx - row * 13) * 4;
            int d = rowbase + row;
            float4 v = make_float4(0.f, 0.f, 0.f, 0.f);
            if (d < N) v = *(const float4*)&sacc[(size_t)d * 52 + q4];
            ushort4 hi, lo;
            hi.x = f2b(v.x); lo.x = f2b(v.x - b2f(hi.x));
            hi.y = f2b(v.y); lo.y = f2b(v.y - b2f(hi.y));
            hi.z = f2b(v.z); lo.z = f2b(v.z - b2f(hi.z));
            hi.w = f2b(v.w); lo.w = f2b(v.w - b2f(hi.w));
            *(ushort4*)&sa[row * 136 + q4] = hi;
            *(ushort4*)&sa[row * 136 + 52 + q4] = lo;
        }
    }
    // ---- zero tails: the MFMA loop reads K-cols [0,128) of both tiles ----
    {
        ushort4 z; z.x = 0; z.y = 0; z.z = 0; z.w = 0;
        // A cols 104..127: 128 rows x 24 shorts = 6 ushort4/row = 768 tasks
        // (R10/R13 bug: only 3 ushort4/row -> cols 116..127 stayed garbage)
#pragma unroll
        for (int k = 0; k < 3; ++k) {
            int idx = tid + k * 256;              // 768 = 3*256 exact
            int row = idx / 6;
            int sp = (idx - row * 6) * 4;
            *(ushort4*)&sa[row * 136 + 104 + sp] = z;
        }
        // B cols 104..127: 64 rows x 6 ushort4 = 384 tasks
#pragma unroll
        for (int k = 0; k < 2; ++k) {
            int idx = tid + k * 256;
            if (idx < 384) {
                int h = idx / 6;
                int sp = (idx - h * 6) * 4;
                *(ushort4*)&swt[h * 136 + 104 + sp] = z;
            }
        }
    }
    // ---- stage B: [W5;b5] -> swt[h][j] and swt[h][52+j]; j==51 -> 0 ----
#pragma unroll
    for (int k = 0; k < 13; ++k) {
        int idx = tid + k * 256;
        int j = idx >> 6;
        int h = idx & 63;
        float wv = 0.f;
        if (j < 48)      wv = W5[j * 64 + h];
        else if (j < 51) wv = b5[(j - 48) * 64 + h];
        unsigned short wb = f2b(wv);
        swt[h * 136 + j] = wb;
        swt[h * 136 + 52 + j] = wb;
    }
    __syncthreads();

    int lane = tid & 63;
    int wid  = tid >> 6;
    int q    = lane >> 4;
    int cc   = lane & 15;
    int m0   = wid * 32;

    f32x4 acc[2][4];
#pragma unroll
    for (int s = 0; s < 2; ++s)
#pragma unroll
        for (int t = 0; t < 4; ++t)
            acc[s][t] = (f32x4){0.f, 0.f, 0.f, 0.f};

#pragma unroll
    for (int k0 = 0; k0 < 128; k0 += 32) {
        int ko = k0 + q * 8;
        short8 af0 = *(short8*)&sa[(m0 + cc) * 136 + ko];
        short8 af1 = *(short8*)&sa[(m0 + 16 + cc) * 136 + ko];
#pragma unroll
        for (int t = 0; t < 4; ++t) {
            short8 bf = *(short8*)&swt[(t * 16 + cc) * 136 + ko];
            acc[0][t] = __builtin_amdgcn_mfma_f32_16x16x32_bf16(
                af0, bf, acc[0][t], 0, 0, 0);
            acc[1][t] = __builtin_amdgcn_mfma_f32_16x16x32_bf16(
                af1, bf, acc[1][t], 0, 0, 0);
        }
    }

    // C/D layout: col = lane&15, row = quad*4 + reg; RMW out (stream-ordered
    // after K2's atomics -> exclusive access here)
#pragma unroll
    for (int s = 0; s < 2; ++s)
#pragma unroll
        for (int reg = 0; reg < 4; ++reg) {
            int rl_ = m0 + s * 16 + q * 4 + reg;
            int r = rowbase + rl_;
            if (r < N) {
#pragma unroll
                for (int t = 0; t < 4; ++t) {
                    float* po = &out[(size_t)r * 64 + t * 16 + cc];
                    *po += acc[s][t][reg];
                }
            }
        }
}

extern "C" void kernel_launch(void* const* d_in, const int* in_sizes, int n_in,
                              void* d_out, int out_size, void* d_ws, size_t ws_size,
                              hipStream_t stream) {
    const float* x  = (const float*)d_in[0];
    const float* ef = (const float*)d_in[1];
    const int* nt   = (const int*)d_in[2];
    const int* es   = (const int*)d_in[3];
    const int* ed   = (const int*)d_in[4];
    const int* et   = (const int*)d_in[5];
    const float* W1 = (const float*)d_in[6];
    const float* b1 = (const float*)d_in[7];
    const float* W2 = (const float*)d_in[8];
    const float* b2 = (const float*)d_in[9];
    // d_in[10..13] = W3,b3,W4,b4 dead (score == 1.0)
    const float* W5 = (const float*)d_in[14];
    const float* b5 = (const float*)d_in[15];

    int N = in_sizes[2];
    int M = in_sizes[3];

    char* w = (char*)d_ws;
    size_t off = 0;
    unsigned short* h2b = (unsigned short*)(w + off); off += (size_t)N * 64 * 2;  // 12.8 MB
    off = (off + 255) & ~(size_t)255;
    int2* rec = (int2*)(w + off); off += (size_t)N * CAP * 8;                     // 12.8 MB
    off = (off + 255) & ~(size_t)255;
    int4* ovf = (int4*)(w + off); off += (size_t)OVF_CAP * 16;                    // 0.5 MB
    off = (off + 255) & ~(size_t)255;
    float* sacc = (float*)(w + off); off += (size_t)N * 52 * 4;                   // 20.8 MB
    off = (off + 255) & ~(size_t)255;
    // zero block: [ovfCnt:1 int][pad->64 B][cnt32: N ints]
    int* ovfCnt = (int*)(w + off);
    int* cnt32  = (int*)(w + off + 64);
    size_t zeroBytes = 64 + (size_t)N * 4;

    float* out = (float*)d_out;

    hipMemsetAsync(ovfCnt, 0, zeroBytes, stream);

    int gemmBlocks    = (N + 127) / 128;    // 782
    int scatterBlocks = (M + 1023) / 1024;  // 782
    int gb1 = 2 * max(gemmBlocks, scatterBlocks);
    k1_gemm_scatter<<<gb1, 256, 0, stream>>>(
        x, nt, W1, b1, W2, b2, es, ed, et,
        cnt32, ovfCnt, ovf, rec, out, h2b, N, M);

    int gatherBlocks = (N + 3) / 4;         // 25000
    int ovfBlocks = 32;
    k2_gather<<<gatherBlocks + ovfBlocks, 256, 0, stream>>>(
        ef, rec, cnt32, W5, b5, ovf, ovfCnt, h2b, out, sacc,
        N, gatherBlocks, ovfBlocks);

    int k3Blocks = (N + 127) / 128;         // 782
    k3_sacc_gemm<<<k3Blocks, 256, 0, stream>>>(sacc, W5, b5, out, N);
}

// Round 8
// 309.304 us; speedup vs baseline: 1.1672x; 1.0161x over previous
//
#include <hip/hip_runtime.h>

// N=100000 nodes, M=800000 edges, F_IN=64, F_E=16, H=64, T_NODE=2, T_EDGE=3.
// score == softmax over singleton axis == 1.0 exactly, so h3/h4/num are dead:
//   out[n] = h1[n] + sum_{e: dst=n} ( h2[src_e] + ef_e . W5[t_e] + b5[t_e] )
//
// R15: K3 fused back into K2 (R14 measured K2+K3 ~= 123us vs R7's fused 101:
// the sacc HBM round-trip + 4th launch ate the win). New K2: each block owns
// 32 dsts (8/wave). Phase 1 = R14's proven edge loop, accS -> LDS A-tile
// (hi/lo bf16, K3's exact [.][136] layout), accH -> sH[32][66]. One barrier.
// Phase 2 = 8 MFMAs/wave (K3's proven fragment/C-layout), epilogue atomically
// adds acc + accH to out. sacc workspace and k3 launch deleted.
//  K1: parity-interleaved MFMA node gemm / slot scatter (unchanged, proven).

#define CAP 16
#define OVF_CAP 32768

typedef __attribute__((ext_vector_type(8))) short short8;
typedef __attribute__((ext_vector_type(4))) float f32x4;

__device__ __forceinline__ float b2f(unsigned short u) {
    union { unsigned v; float f; } x; x.v = ((unsigned)u) << 16; return x.f;
}
__device__ __forceinline__ unsigned short f2b(float f) {
    union { float f; unsigned v; } x; x.f = f;
    unsigned u = x.v;
    unsigned r = (u + 0x7FFFu + ((u >> 16) & 1u)) >> 16;
    return (unsigned short)r;
}

// ---------------- K1: gemm (even blocks) || slot scatter (odd blocks) -------
__global__ __launch_bounds__(256) void k1_gemm_scatter(
    const float* __restrict__ x, const int* __restrict__ nt,
    const float* __restrict__ W1, const float* __restrict__ b1,
    const float* __restrict__ W2, const float* __restrict__ b2,
    const int* __restrict__ esrc, const int* __restrict__ edst,
    const int* __restrict__ etype,
    int* __restrict__ cnt32, int* __restrict__ ovfCnt,
    int4* __restrict__ ovf, int2* __restrict__ rec,
    float* __restrict__ out, unsigned short* __restrict__ h2b,
    int N, int M)
{
    // 72 = 64 + 8 pad: row stride 144 B -> 2-way bank alias (free)
    __shared__ __align__(16) unsigned short sx[128 * 72];     // 18 KB
    __shared__ __align__(16) unsigned short sw[4][64 * 72];   // 36 KB
    __shared__ int snt[128];

    int tid = threadIdx.x;

    if (blockIdx.x & 1) {
        // ---------------- scatter path: 1024 edges/block, 4 per thread ------
        int e0 = (blockIdx.x >> 1) * 1024 + tid;
        int dd[4], ssrc[4], tty[4];
        bool v[4];
#pragma unroll
        for (int j = 0; j < 4; ++j) {
            int e = e0 + j * 256;
            v[j] = e < M;
            int ec = v[j] ? e : 0;
            dd[j]   = edst[ec];
            ssrc[j] = esrc[ec];
            tty[j]  = etype[ec];
        }
        int pos[4];
#pragma unroll
        for (int j = 0; j < 4; ++j)
            if (v[j]) pos[j] = atomicAdd(&cnt32[dd[j]], 1);
#pragma unroll
        for (int j = 0; j < 4; ++j) {
            if (!v[j]) continue;
            int packed = ssrc[j] | (tty[j] << 20);
            int e = e0 + j * 256;
            if (pos[j] < CAP) {
                rec[dd[j] * CAP + pos[j]] = make_int2(packed, e);
            } else {
                int slot = atomicAdd(ovfCnt, 1);
                if (slot < OVF_CAP) ovf[slot] = make_int4(packed, e, dd[j], 0);
            }
        }
        return;
    }

    // ---------------- gemm path: 128 rows x 64 h, 4 weight mats -------------
    int rowbase = (blockIdx.x >> 1) * 128;

    const float* Wm0 = W1;            // [k][n] fp32, type 0
    const float* Wm1 = W1 + 4096;     // type 1
    const float* Wm2 = W2;
    const float* Wm3 = W2 + 4096;
#pragma unroll
    for (int j = 0; j < 4; ++j) {
        int k  = (tid >> 4) + j * 16;
        int n4 = (tid & 15) * 4;
        float4 w0 = *(const float4*)&Wm0[k * 64 + n4];
        float4 w1v = *(const float4*)&Wm1[k * 64 + n4];
        float4 w2v = *(const float4*)&Wm2[k * 64 + n4];
        float4 w3 = *(const float4*)&Wm3[k * 64 + n4];
        sw[0][(n4 + 0) * 72 + k] = f2b(w0.x);
        sw[0][(n4 + 1) * 72 + k] = f2b(w0.y);
        sw[0][(n4 + 2) * 72 + k] = f2b(w0.z);
        sw[0][(n4 + 3) * 72 + k] = f2b(w0.w);
        sw[1][(n4 + 0) * 72 + k] = f2b(w1v.x);
        sw[1][(n4 + 1) * 72 + k] = f2b(w1v.y);
        sw[1][(n4 + 2) * 72 + k] = f2b(w1v.z);
        sw[1][(n4 + 3) * 72 + k] = f2b(w1v.w);
        sw[2][(n4 + 0) * 72 + k] = f2b(w2v.x);
        sw[2][(n4 + 1) * 72 + k] = f2b(w2v.y);
        sw[2][(n4 + 2) * 72 + k] = f2b(w2v.z);
        sw[2][(n4 + 3) * 72 + k] = f2b(w2v.w);
        sw[3][(n4 + 0) * 72 + k] = f2b(w3.x);
        sw[3][(n4 + 1) * 72 + k] = f2b(w3.y);
        sw[3][(n4 + 2) * 72 + k] = f2b(w3.z);
        sw[3][(n4 + 3) * 72 + k] = f2b(w3.w);
    }

    if (tid < 128) {
        int r = rowbase + tid;
        snt[tid] = (r < N) ? nt[r] : 0;
    }

    // stage x tile (contiguous rows, no perm)
    int fr = (tid & 15) * 4;
    int ir = tid >> 4;
#pragma unroll
    for (int it = 0; it < 8; ++it) {
        int i = it * 16 + ir;
        int r = rowbase + i;
        float4 v = make_float4(0.f, 0.f, 0.f, 0.f);
        if (r < N) v = *(const float4*)&x[(size_t)r * 64 + fr];
        ushort4 p;
        p.x = f2b(v.x); p.y = f2b(v.y); p.z = f2b(v.z); p.w = f2b(v.w);
        *(ushort4*)&sx[i * 72 + fr] = p;
    }
    __syncthreads();

    int lane = tid & 63;
    int wid  = tid >> 6;
    int q    = lane >> 4;
    int cc   = lane & 15;
    int m0   = wid * 32;

    f32x4 acc[4][2][4];   // [mat][s][t]
#pragma unroll
    for (int mm = 0; mm < 4; ++mm)
#pragma unroll
        for (int s = 0; s < 2; ++s)
#pragma unroll
            for (int t = 0; t < 4; ++t)
                acc[mm][s][t] = (f32x4){0.f, 0.f, 0.f, 0.f};

#pragma unroll
    for (int k0 = 0; k0 < 64; k0 += 32) {
        int ko = k0 + q * 8;
        short8 af0 = *(short8*)&sx[(m0 + cc) * 72 + ko];
        short8 af1 = *(short8*)&sx[(m0 + 16 + cc) * 72 + ko];
#pragma unroll
        for (int mm = 0; mm < 4; ++mm)
#pragma unroll
            for (int t = 0; t < 4; ++t) {
                short8 bf = *(short8*)&sw[mm][(t * 16 + cc) * 72 + ko];
                acc[mm][0][t] = __builtin_amdgcn_mfma_f32_16x16x32_bf16(
                    af0, bf, acc[mm][0][t], 0, 0, 0);
                acc[mm][1][t] = __builtin_amdgcn_mfma_f32_16x16x32_bf16(
                    af1, bf, acc[mm][1][t], 0, 0, 0);
            }
    }

    float b1v[2][4], b2v[2][4];
#pragma unroll
    for (int ty = 0; ty < 2; ++ty)
#pragma unroll
        for (int t = 0; t < 4; ++t) {
            b1v[ty][t] = b1[ty * 64 + t * 16 + cc];
            b2v[ty][t] = b2[ty * 64 + t * 16 + cc];
        }

    // C/D layout: col = lane&15, row = quad*4 + reg
#pragma unroll
    for (int s = 0; s < 2; ++s)
#pragma unroll
        for (int reg = 0; reg < 4; ++reg) {
            int rl_ = m0 + s * 16 + q * 4 + reg;
            int r = rowbase + rl_;
            if (r < N) {
                int ty = snt[rl_];
#pragma unroll
                for (int t = 0; t < 4; ++t) {
                    float v1 = (ty ? acc[1][s][t][reg] : acc[0][s][t][reg])
                               + b1v[ty][t];
                    float v2 = (ty ? acc[3][s][t][reg] : acc[2][s][t][reg])
                               + b2v[ty][t];
                    out[(size_t)r * 64 + t * 16 + cc] = v1;
                    h2b[(size_t)r * 64 + t * 16 + cc] = f2b(v2);
                }
            }
        }
}

// ---------------- K2: gather + fused MFMA matvec (32 dsts / block) ----------
// Phase 1 (per wave, 8 dsts): edge loop accumulates accH (h2 row sum) and
//   accS (51-vector); lanes<52 write accS hi/lo bf16 into sa[wd][0..103]
//   (cols 104..127 zeroed separately; col 51/103 are accS[51]==0),
//   accH -> sH[wd][lane].
// Phase 2 (after barrier): C[32x64] = sa * swt via 8 MFMAs/wave; epilogue
//   atomicAdd(out[d][col], C + sH) (atomic: ovf tail blocks touch same rows).
__global__ __launch_bounds__(256) void k2_gather_mm(
    const float* __restrict__ ef, const int2* __restrict__ rec,
    const int* __restrict__ cnt32,
    const float* __restrict__ W5, const float* __restrict__ b5,
    const int4* __restrict__ ovf, const int* __restrict__ ovfCnt,
    const unsigned short* __restrict__ h2b, float* __restrict__ out,
    int N, int gatherBlocks, int ovfBlocks)
{
    __shared__ __align__(16) unsigned short sa[32 * 136];    // 8.5 KB A tile
    __shared__ __align__(16) unsigned short swt[64 * 136];   // 17 KB  B tile
    __shared__ __align__(16) float sH[32 * 66];              // 8.25 KB accH

    int tid = threadIdx.x;
    int lane = tid & 63;
    int wid = tid >> 6;

    if (blockIdx.x >= (unsigned)gatherBlocks) {
        // ---- overflow fixup: grid-stride waves over ovf list (rare) ----
        int novf = min(*ovfCnt, OVF_CAP);
        int gw = (blockIdx.x - gatherBlocks) * 4 + wid;
        int nw = ovfBlocks * 4;
        for (int ri = gw; ri < novf; ri += nw) {
            int4 o = ovf[ri];
            int s = o.x & 0xFFFFF;
            int t = (unsigned)o.x >> 20;
            float acc = b5[t * 64 + lane] + b2f(h2b[((size_t)s << 6) | lane]);
#pragma unroll
            for (int f = 0; f < 16; ++f)
                acc = fmaf(ef[(size_t)o.y * 16 + f],
                           W5[(t * 16 + f) * 64 + lane], acc);
            unsafeAtomicAdd(&out[(size_t)o.z * 64 + lane], acc);
        }
        return;
    }

    // ---- stage B: [W5;b5] -> swt[h][j], swt[h][52+j]; j==51 -> 0 (R14) ----
#pragma unroll
    for (int k = 0; k < 13; ++k) {
        int idx = tid + k * 256;                  // 3328 = 52*64 exact
        int j = idx >> 6;
        int h = idx & 63;
        float wv = 0.f;
        if (j < 48)      wv = W5[j * 64 + h];
        else if (j < 51) wv = b5[(j - 48) * 64 + h];
        unsigned short wb = f2b(wv);
        swt[h * 136 + j] = wb;
        swt[h * 136 + 52 + j] = wb;
    }
    {
        ushort4 z; z.x = 0; z.y = 0; z.z = 0; z.w = 0;
        // B cols 104..127: 64 rows x 6 ushort4 = 384 tasks (R14-verified)
#pragma unroll
        for (int k = 0; k < 2; ++k) {
            int idx = tid + k * 256;
            if (idx < 384) {
                int h = idx / 6;
                int sp = (idx - h * 6) * 4;
                *(ushort4*)&swt[h * 136 + 104 + sp] = z;
            }
        }
        // A cols 104..127: 32 rows x 6 ushort4 = 192 tasks
        if (tid < 192) {
            int row = tid / 6;
            int sp = (tid - row * 6) * 4;
            *(ushort4*)&sa[row * 136 + 104 + sp] = z;
        }
    }

    // ---- phase 1: 8 dsts per wave, R14's proven edge loop ----
    int myt = (lane < 48) ? (lane >> 4) : (lane - 48);
    unsigned myf = lane & 15;
    bool fl = lane < 48;
    int wbase = blockIdx.x * 32 + wid * 8;

#pragma unroll 1
    for (int g = 0; g < 8; ++g) {
        int d = wbase + g;
        int dg = (d < N) ? min(cnt32[d], CAP) : 0;
        unsigned base = (unsigned)d * CAP;

        float accH = 0.f, accS = 0.f;
        float hLast = 0.f, vLast = 0.f;
        int tLast = -1;
        int dgm1 = dg - 1;

        for (int i = 0; i < dg; i += 8) {
            int2 r[8];
#pragma unroll
            for (int j = 0; j < 8; ++j) {
                int ij = min(i + j, dgm1);        // clamp to written slots
                r[j] = rec[base + ij];
            }
            float hv[8], ev[8];
#pragma unroll
            for (int j = 0; j < 8; ++j) {
                unsigned s = (unsigned)r[j].x & 0xFFFFFu;
                hv[j] = b2f(h2b[((size_t)s << 6) | (unsigned)lane]);
                ev[j] = ef[((unsigned)r[j].y << 4) | myf];
            }
#pragma unroll
            for (int j = 0; j < 8; ++j) {
                int t = (int)((unsigned)r[j].x >> 20);
                float v = fl ? ev[j] : 1.0f;
                accH += hv[j];
                accS += (t == myt) ? v : 0.f;
                hLast = hv[j]; vLast = v; tLast = t;
            }
        }
        // slots past dg re-read record dg-1: subtract the duplicates once
        float fd = (float)(((dg + 7) & ~7) - dg);
        accH -= fd * hLast;
        accS -= (tLast == myt) ? fd * vLast : 0.f;

        int wd = wid * 8 + g;
        if (lane < 52) {
            unsigned short hi = f2b(accS);
            unsigned short lo = f2b(accS - b2f(hi));
            sa[wd * 136 + lane] = hi;             // cols 0..51 (51 == 0)
            sa[wd * 136 + 52 + lane] = lo;        // cols 52..103
        }
        sH[wd * 66 + lane] = accH;
    }
    __syncthreads();

    // ---- phase 2: C[32x64] via MFMA; wave -> row-tile (wid&1),
    //      col-tiles {wid>>1, (wid>>1)+2}  (K3's fragment/C layout) ----
    int q  = lane >> 4;
    int cc = lane & 15;
    int s  = wid & 1;
    int t0 = wid >> 1;

    f32x4 acc0 = (f32x4){0.f, 0.f, 0.f, 0.f};
    f32x4 acc1 = (f32x4){0.f, 0.f, 0.f, 0.f};
#pragma unroll
    for (int k0 = 0; k0 < 128; k0 += 32) {
        int ko = k0 + q * 8;
        short8 af = *(short8*)&sa[(s * 16 + cc) * 136 + ko];
        short8 bf0 = *(short8*)&swt[(t0 * 16 + cc) * 136 + ko];
        short8 bf1 = *(short8*)&swt[((t0 + 2) * 16 + cc) * 136 + ko];
        acc0 = __builtin_amdgcn_mfma_f32_16x16x32_bf16(af, bf0, acc0, 0, 0, 0);
        acc1 = __builtin_amdgcn_mfma_f32_16x16x32_bf16(af, bf1, acc1, 0, 0, 0);
    }

    // C/D layout: col = lane&15, row = quad*4 + reg
#pragma unroll
    for (int reg = 0; reg < 4; ++reg) {
        int rl = s * 16 + q * 4 + reg;
        int d = blockIdx.x * 32 + rl;
        if (d < N) {
            int c0 = t0 * 16 + cc;
            int c1 = (t0 + 2) * 16 + cc;
            float v0 = acc0[reg] + sH[rl * 66 + c0];
            float v1 = acc1[reg] + sH[rl * 66 + c1];
            unsafeAtomicAdd(&out[(size_t)d * 64 + c0], v0);
            unsafeAtomicAdd(&out[(size_t)d * 64 + c1], v1);
        }
    }
}

extern "C" void kernel_launch(void* const* d_in, const int* in_sizes, int n_in,
                              void* d_out, int out_size, void* d_ws, size_t ws_size,
                              hipStream_t stream) {
    const float* x  = (const float*)d_in[0];
    const float* ef = (const float*)d_in[1];
    const int* nt   = (const int*)d_in[2];
    const int* es   = (const int*)d_in[3];
    const int* ed   = (const int*)d_in[4];
    const int* et   = (const int*)d_in[5];
    const float* W1 = (const float*)d_in[6];
    const float* b1 = (const float*)d_in[7];
    const float* W2 = (const float*)d_in[8];
    const float* b2 = (const float*)d_in[9];
    // d_in[10..13] = W3,b3,W4,b4 dead (score == 1.0)
    const float* W5 = (const float*)d_in[14];
    const float* b5 = (const float*)d_in[15];

    int N = in_sizes[2];
    int M = in_sizes[3];

    char* w = (char*)d_ws;
    size_t off = 0;
    unsigned short* h2b = (unsigned short*)(w + off); off += (size_t)N * 64 * 2;  // 12.8 MB
    off = (off + 255) & ~(size_t)255;
    int2* rec = (int2*)(w + off); off += (size_t)N * CAP * 8;                     // 12.8 MB
    off = (off + 255) & ~(size_t)255;
    int4* ovf = (int4*)(w + off); off += (size_t)OVF_CAP * 16;                    // 0.5 MB
    off = (off + 255) & ~(size_t)255;
    // zero block: [ovfCnt:1 int][pad->64 B][cnt32: N ints]
    int* ovfCnt = (int*)(w + off);
    int* cnt32  = (int*)(w + off + 64);
    size_t zeroBytes = 64 + (size_t)N * 4;

    float* out = (float*)d_out;

    hipMemsetAsync(ovfCnt, 0, zeroBytes, stream);

    int gemmBlocks    = (N + 127) / 128;    // 782
    int scatterBlocks = (M + 1023) / 1024;  // 782
    int gb1 = 2 * max(gemmBlocks, scatterBlocks);
    k1_gemm_scatter<<<gb1, 256, 0, stream>>>(
        x, nt, W1, b1, W2, b2, es, ed, et,
        cnt32, ovfCnt, ovf, rec, out, h2b, N, M);

    int gatherBlocks = (N + 31) / 32;       // 3125
    int ovfBlocks = 32;
    k2_gather_mm<<<gatherBlocks + ovfBlocks, 256, 0, stream>>>(
        ef, rec, cnt32, W5, b5, ovf, ovfCnt, h2b, out,
        N, gatherBlocks, ovfBlocks);
}

// Round 9
// 298.587 us; speedup vs baseline: 1.2090x; 1.0359x over previous
//
#include <hip/hip_runtime.h>

// N=100000 nodes, M=800000 edges, F_IN=64, F_E=16, H=64, T_NODE=2, T_EDGE=3.
// score == softmax over singleton axis == 1.0 exactly, so h3/h4/num are dead:
//   out[n] = h1[n] + sum_{e: dst=n} ( h2[src_e] + ef_e . W5[t_e] + b5[t_e] )
//
// R16: K2 concurrency push (R15 measured: traffic already at the algorithmic
// minimum, 99MB fetch, but only 1.17 TB/s effective -> latency-bound at 38%
// occupancy with ~1 line in flight per wave).
//  (a) LDS 34.8->25.9 KB: B tile deduped (A = [hi|0|lo|0] K=128, B indexed
//      ko&63, stride 72) -> 6 blocks/CU.
//  (b) pair-pipelined edge loop: both dsts' rec batches issued (uniform ->
//      s_load), then both h2b/ef batches (2x lines in flight), ok-predicated
//      accumulate (replaces dup-subtract; masked stale slots -> addr 0).
//  (c) atomics only for rows with cnt>CAP (ovf-shared); plain RMW otherwise.
//  K1: parity-interleaved MFMA node gemm / slot scatter (unchanged, proven).

#define CAP 16
#define OVF_CAP 32768

typedef __attribute__((ext_vector_type(8))) short short8;
typedef __attribute__((ext_vector_type(4))) float f32x4;

__device__ __forceinline__ float b2f(unsigned short u) {
    union { unsigned v; float f; } x; x.v = ((unsigned)u) << 16; return x.f;
}
__device__ __forceinline__ unsigned short f2b(float f) {
    union { float f; unsigned v; } x; x.f = f;
    unsigned u = x.v;
    unsigned r = (u + 0x7FFFu + ((u >> 16) & 1u)) >> 16;
    return (unsigned short)r;
}

// ---------------- K1: gemm (even blocks) || slot scatter (odd blocks) -------
__global__ __launch_bounds__(256) void k1_gemm_scatter(
    const float* __restrict__ x, const int* __restrict__ nt,
    const float* __restrict__ W1, const float* __restrict__ b1,
    const float* __restrict__ W2, const float* __restrict__ b2,
    const int* __restrict__ esrc, const int* __restrict__ edst,
    const int* __restrict__ etype,
    int* __restrict__ cnt32, int* __restrict__ ovfCnt,
    int4* __restrict__ ovf, int2* __restrict__ rec,
    float* __restrict__ out, unsigned short* __restrict__ h2b,
    int N, int M)
{
    // 72 = 64 + 8 pad: row stride 144 B -> 2-way bank alias (free)
    __shared__ __align__(16) unsigned short sx[128 * 72];     // 18 KB
    __shared__ __align__(16) unsigned short sw[4][64 * 72];   // 36 KB
    __shared__ int snt[128];

    int tid = threadIdx.x;

    if (blockIdx.x & 1) {
        // ---------------- scatter path: 1024 edges/block, 4 per thread ------
        int e0 = (blockIdx.x >> 1) * 1024 + tid;
        int dd[4], ssrc[4], tty[4];
        bool v[4];
#pragma unroll
        for (int j = 0; j < 4; ++j) {
            int e = e0 + j * 256;
            v[j] = e < M;
            int ec = v[j] ? e : 0;
            dd[j]   = edst[ec];
            ssrc[j] = esrc[ec];
            tty[j]  = etype[ec];
        }
        int pos[4];
#pragma unroll
        for (int j = 0; j < 4; ++j)
            if (v[j]) pos[j] = atomicAdd(&cnt32[dd[j]], 1);
#pragma unroll
        for (int j = 0; j < 4; ++j) {
            if (!v[j]) continue;
            int packed = ssrc[j] | (tty[j] << 20);
            int e = e0 + j * 256;
            if (pos[j] < CAP) {
                rec[dd[j] * CAP + pos[j]] = make_int2(packed, e);
            } else {
                int slot = atomicAdd(ovfCnt, 1);
                if (slot < OVF_CAP) ovf[slot] = make_int4(packed, e, dd[j], 0);
            }
        }
        return;
    }

    // ---------------- gemm path: 128 rows x 64 h, 4 weight mats -------------
    int rowbase = (blockIdx.x >> 1) * 128;

    const float* Wm0 = W1;            // [k][n] fp32, type 0
    const float* Wm1 = W1 + 4096;     // type 1
    const float* Wm2 = W2;
    const float* Wm3 = W2 + 4096;
#pragma unroll
    for (int j = 0; j < 4; ++j) {
        int k  = (tid >> 4) + j * 16;
        int n4 = (tid & 15) * 4;
        float4 w0 = *(const float4*)&Wm0[k * 64 + n4];
        float4 w1v = *(const float4*)&Wm1[k * 64 + n4];
        float4 w2v = *(const float4*)&Wm2[k * 64 + n4];
        float4 w3 = *(const float4*)&Wm3[k * 64 + n4];
        sw[0][(n4 + 0) * 72 + k] = f2b(w0.x);
        sw[0][(n4 + 1) * 72 + k] = f2b(w0.y);
        sw[0][(n4 + 2) * 72 + k] = f2b(w0.z);
        sw[0][(n4 + 3) * 72 + k] = f2b(w0.w);
        sw[1][(n4 + 0) * 72 + k] = f2b(w1v.x);
        sw[1][(n4 + 1) * 72 + k] = f2b(w1v.y);
        sw[1][(n4 + 2) * 72 + k] = f2b(w1v.z);
        sw[1][(n4 + 3) * 72 + k] = f2b(w1v.w);
        sw[2][(n4 + 0) * 72 + k] = f2b(w2v.x);
        sw[2][(n4 + 1) * 72 + k] = f2b(w2v.y);
        sw[2][(n4 + 2) * 72 + k] = f2b(w2v.z);
        sw[2][(n4 + 3) * 72 + k] = f2b(w2v.w);
        sw[3][(n4 + 0) * 72 + k] = f2b(w3.x);
        sw[3][(n4 + 1) * 72 + k] = f2b(w3.y);
        sw[3][(n4 + 2) * 72 + k] = f2b(w3.z);
        sw[3][(n4 + 3) * 72 + k] = f2b(w3.w);
    }

    if (tid < 128) {
        int r = rowbase + tid;
        snt[tid] = (r < N) ? nt[r] : 0;
    }

    // stage x tile (contiguous rows, no perm)
    int fr = (tid & 15) * 4;
    int ir = tid >> 4;
#pragma unroll
    for (int it = 0; it < 8; ++it) {
        int i = it * 16 + ir;
        int r = rowbase + i;
        float4 v = make_float4(0.f, 0.f, 0.f, 0.f);
        if (r < N) v = *(const float4*)&x[(size_t)r * 64 + fr];
        ushort4 p;
        p.x = f2b(v.x); p.y = f2b(v.y); p.z = f2b(v.z); p.w = f2b(v.w);
        *(ushort4*)&sx[i * 72 + fr] = p;
    }
    __syncthreads();

    int lane = tid & 63;
    int wid  = tid >> 6;
    int q    = lane >> 4;
    int cc   = lane & 15;
    int m0   = wid * 32;

    f32x4 acc[4][2][4];   // [mat][s][t]
#pragma unroll
    for (int mm = 0; mm < 4; ++mm)
#pragma unroll
        for (int s = 0; s < 2; ++s)
#pragma unroll
            for (int t = 0; t < 4; ++t)
                acc[mm][s][t] = (f32x4){0.f, 0.f, 0.f, 0.f};

#pragma unroll
    for (int k0 = 0; k0 < 64; k0 += 32) {
        int ko = k0 + q * 8;
        short8 af0 = *(short8*)&sx[(m0 + cc) * 72 + ko];
        short8 af1 = *(short8*)&sx[(m0 + 16 + cc) * 72 + ko];
#pragma unroll
        for (int mm = 0; mm < 4; ++mm)
#pragma unroll
            for (int t = 0; t < 4; ++t) {
                short8 bf = *(short8*)&sw[mm][(t * 16 + cc) * 72 + ko];
                acc[mm][0][t] = __builtin_amdgcn_mfma_f32_16x16x32_bf16(
                    af0, bf, acc[mm][0][t], 0, 0, 0);
                acc[mm][1][t] = __builtin_amdgcn_mfma_f32_16x16x32_bf16(
                    af1, bf, acc[mm][1][t], 0, 0, 0);
            }
    }

    float b1v[2][4], b2v[2][4];
#pragma unroll
    for (int ty = 0; ty < 2; ++ty)
#pragma unroll
        for (int t = 0; t < 4; ++t) {
            b1v[ty][t] = b1[ty * 64 + t * 16 + cc];
            b2v[ty][t] = b2[ty * 64 + t * 16 + cc];
        }

    // C/D layout: col = lane&15, row = quad*4 + reg
#pragma unroll
    for (int s = 0; s < 2; ++s)
#pragma unroll
        for (int reg = 0; reg < 4; ++reg) {
            int rl_ = m0 + s * 16 + q * 4 + reg;
            int r = rowbase + rl_;
            if (r < N) {
                int ty = snt[rl_];
#pragma unroll
                for (int t = 0; t < 4; ++t) {
                    float v1 = (ty ? acc[1][s][t][reg] : acc[0][s][t][reg])
                               + b1v[ty][t];
                    float v2 = (ty ? acc[3][s][t][reg] : acc[2][s][t][reg])
                               + b2v[ty][t];
                    out[(size_t)r * 64 + t * 16 + cc] = v1;
                    h2b[(size_t)r * 64 + t * 16 + cc] = f2b(v2);
                }
            }
        }
}

// ---------------- K2: gather + fused MFMA matvec (32 dsts / block) ----------
// Phase 1 (per wave, 8 dsts in pairs): edge loops accumulate accH/accS for
//   two dsts with all loads batched (2x lines in flight). accS -> sa rows
//   [hi(0..51)|0|lo(64..115)|0], accH -> sH, raw cnt -> sCnt.
// Phase 2: C[32x64] = sa * swt (B deduped: swt[h][k&63], 52 real cols);
//   epilogue adds C + sH to out; plain RMW unless row has cnt>CAP (then
//   atomic, shared with the ovf fixup blocks).
__global__ __launch_bounds__(256) void k2_gather_mm(
    const float* __restrict__ ef, const int2* __restrict__ rec,
    const int* __restrict__ cnt32,
    const float* __restrict__ W5, const float* __restrict__ b5,
    const int4* __restrict__ ovf, const int* __restrict__ ovfCnt,
    const unsigned short* __restrict__ h2b, float* __restrict__ out,
    int N, int gatherBlocks, int ovfBlocks)
{
    __shared__ __align__(16) unsigned short sa[32 * 136];    // 8.5 KB A tile
    __shared__ __align__(16) unsigned short swt[64 * 72];    // 9 KB   B tile
    __shared__ __align__(16) float sH[32 * 66];              // 8.25 KB accH
    __shared__ int sCnt[32];

    int tid = threadIdx.x;
    int lane = tid & 63;
    int wid = tid >> 6;

    if (blockIdx.x >= (unsigned)gatherBlocks) {
        // ---- overflow fixup: grid-stride waves over ovf list (rare) ----
        int novf = min(*ovfCnt, OVF_CAP);
        int gw = (blockIdx.x - gatherBlocks) * 4 + wid;
        int nw = ovfBlocks * 4;
        for (int ri = gw; ri < novf; ri += nw) {
            int4 o = ovf[ri];
            int s = o.x & 0xFFFFF;
            int t = (unsigned)o.x >> 20;
            float acc = b5[t * 64 + lane] + b2f(h2b[((size_t)s << 6) | lane]);
#pragma unroll
            for (int f = 0; f < 16; ++f)
                acc = fmaf(ef[(size_t)o.y * 16 + f],
                           W5[(t * 16 + f) * 64 + lane], acc);
            unsafeAtomicAdd(&out[(size_t)o.z * 64 + lane], acc);
        }
        return;
    }

    // ---- stage B: [W5;b5] -> swt[h][j], j<52 (j==51 -> 0; R14 lesson) ----
#pragma unroll
    for (int k = 0; k < 13; ++k) {
        int idx = tid + k * 256;                  // 3328 = 52*64 exact
        int j = idx >> 6;
        int h = idx & 63;
        float wv = 0.f;
        if (j < 48)      wv = W5[j * 64 + h];
        else if (j < 51) wv = b5[(j - 48) * 64 + h];
        swt[h * 72 + j] = f2b(wv);
    }
    {
        ushort4 z; z.x = 0; z.y = 0; z.z = 0; z.w = 0;
        // B cols 52..63: 64 rows x 3 ushort4 = 192 tasks (full coverage:
        // 12 cols = 3 ushort4 -- R14 lesson, count the tail width!)
        if (tid < 192) {
            int h = tid / 3;
            int sp = (tid - h * 3) * 4;
            *(ushort4*)&swt[h * 72 + 52 + sp] = z;
        }
        // A cols 52..63 and 116..127: 32 rows x 6 ushort4 = 192 tasks
        if (tid < 192) {
            int row = tid / 6;
            int w6 = tid - row * 6;
            int sp = (w6 < 3) ? (52 + w6 * 4) : (116 + (w6 - 3) * 4);
            *(ushort4*)&sa[row * 136 + sp] = z;
        }
    }

    // ---- phase 1: 8 dsts per wave, processed in pipelined pairs ----
    int myt = (lane < 48) ? (lane >> 4) : (lane - 48);
    unsigned myf = lane & 15;
    bool fl = lane < 48;
    int wbase = blockIdx.x * 32 + wid * 8;

    int cnts[8];
#pragma unroll
    for (int g = 0; g < 8; ++g) {
        int d = wbase + g;
        cnts[g] = (d < N) ? cnt32[d] : 0;
    }
    if (lane == 0) {
#pragma unroll
        for (int g = 0; g < 8; ++g) sCnt[wid * 8 + g] = cnts[g];
    }

#pragma unroll 1
    for (int gp = 0; gp < 8; gp += 2) {
        int dA = wbase + gp, dB = dA + 1;
        int dgA = min(cnts[gp], CAP);
        int dgB = min(cnts[gp + 1], CAP);
        unsigned baseA = (unsigned)(dA < N ? dA : 0) * CAP;
        unsigned baseB = (unsigned)(dB < N ? dB : 0) * CAP;

        // issue both rec batches (wave-uniform -> scalar loads)
        int2 rA[8], rB[8];
#pragma unroll
        for (int j = 0; j < 8; ++j) rA[j] = rec[baseA + j];
#pragma unroll
        for (int j = 0; j < 8; ++j) rB[j] = rec[baseB + j];

        // issue both gather batches (stale slots masked to address 0)
        float hvA[8], evA[8], hvB[8], evB[8];
#pragma unroll
        for (int j = 0; j < 8; ++j) {
            bool ok = j < dgA;
            unsigned s = ok ? ((unsigned)rA[j].x & 0xFFFFFu) : 0u;
            unsigned e = ok ? (unsigned)rA[j].y : 0u;
            hvA[j] = b2f(h2b[((size_t)s << 6) | (unsigned)lane]);
            evA[j] = ef[(e << 4) | myf];
        }
#pragma unroll
        for (int j = 0; j < 8; ++j) {
            bool ok = j < dgB;
            unsigned s = ok ? ((unsigned)rB[j].x & 0xFFFFFu) : 0u;
            unsigned e = ok ? (unsigned)rB[j].y : 0u;
            hvB[j] = b2f(h2b[((size_t)s << 6) | (unsigned)lane]);
            evB[j] = ef[(e << 4) | myf];
        }

        float accHA = 0.f, accSA = 0.f, accHB = 0.f, accSB = 0.f;
#pragma unroll
        for (int j = 0; j < 8; ++j) {
            bool okA = j < dgA;
            int tA = (int)((unsigned)rA[j].x >> 20);
            accHA += okA ? hvA[j] : 0.f;
            float vA = fl ? evA[j] : 1.0f;
            accSA += (okA && tA == myt) ? vA : 0.f;
            bool okB = j < dgB;
            int tB = (int)((unsigned)rB[j].x >> 20);
            accHB += okB ? hvB[j] : 0.f;
            float vB = fl ? evB[j] : 1.0f;
            accSB += (okB && tB == myt) ? vB : 0.f;
        }

        // second chunks (deg > 8): on-demand clamped loads (44% of dsts)
        if (dgA > 8) {
            int2 r2[8];
#pragma unroll
            for (int j = 0; j < 8; ++j)
                r2[j] = rec[baseA + (unsigned)min(8 + j, dgA - 1)];
#pragma unroll
            for (int j = 0; j < 8; ++j) {
                unsigned s = (unsigned)r2[j].x & 0xFFFFFu;
                float hv = b2f(h2b[((size_t)s << 6) | (unsigned)lane]);
                float evv = ef[((unsigned)r2[j].y << 4) | myf];
                int t = (int)((unsigned)r2[j].x >> 20);
                bool ok = (8 + j) < dgA;
                accHA += ok ? hv : 0.f;
                float v = fl ? evv : 1.0f;
                accSA += (ok && t == myt) ? v : 0.f;
            }
        }
        if (dgB > 8) {
            int2 r2[8];
#pragma unroll
            for (int j = 0; j < 8; ++j)
                r2[j] = rec[baseB + (unsigned)min(8 + j, dgB - 1)];
#pragma unroll
            for (int j = 0; j < 8; ++j) {
                unsigned s = (unsigned)r2[j].x & 0xFFFFFu;
                float hv = b2f(h2b[((size_t)s << 6) | (unsigned)lane]);
                float evv = ef[((unsigned)r2[j].y << 4) | myf];
                int t = (int)((unsigned)r2[j].x >> 20);
                bool ok = (8 + j) < dgB;
                accHB += ok ? hv : 0.f;
                float v = fl ? evv : 1.0f;
                accSB += (ok && t == myt) ? v : 0.f;
            }
        }

        int wdA = wid * 8 + gp, wdB = wdA + 1;
        if (lane < 52) {
            unsigned short hiA = f2b(accSA);
            sa[wdA * 136 + lane] = hiA;
            sa[wdA * 136 + 64 + lane] = f2b(accSA - b2f(hiA));
            unsigned short hiB = f2b(accSB);
            sa[wdB * 136 + lane] = hiB;
            sa[wdB * 136 + 64 + lane] = f2b(accSB - b2f(hiB));
        }
        sH[wdA * 66 + lane] = accHA;
        sH[wdB * 66 + lane] = accHB;
    }
    __syncthreads();

    // ---- phase 2: C[32x64] via MFMA; wave -> row-tile (wid&1),
    //      col-tiles {wid>>1, (wid>>1)+2}; B fragment reads ko&63 ----
    int q  = lane >> 4;
    int cc = lane & 15;
    int s  = wid & 1;
    int t0 = wid >> 1;

    f32x4 acc0 = (f32x4){0.f, 0.f, 0.f, 0.f};
    f32x4 acc1 = (f32x4){0.f, 0.f, 0.f, 0.f};
#pragma unroll
    for (int k0 = 0; k0 < 128; k0 += 32) {
        int ko = k0 + q * 8;
        int kb = ko & 63;
        short8 af = *(short8*)&sa[(s * 16 + cc) * 136 + ko];
        short8 bf0 = *(short8*)&swt[(t0 * 16 + cc) * 72 + kb];
        short8 bf1 = *(short8*)&swt[((t0 + 2) * 16 + cc) * 72 + kb];
        acc0 = __builtin_amdgcn_mfma_f32_16x16x32_bf16(af, bf0, acc0, 0, 0, 0);
        acc1 = __builtin_amdgcn_mfma_f32_16x16x32_bf16(af, bf1, acc1, 0, 0, 0);
    }

    // C/D layout: col = lane&15, row = quad*4 + reg
#pragma unroll
    for (int reg = 0; reg < 4; ++reg) {
        int rl = s * 16 + q * 4 + reg;
        int d = blockIdx.x * 32 + rl;
        if (d < N) {
            int c0 = t0 * 16 + cc;
            int c1 = (t0 + 2) * 16 + cc;
            float v0 = acc0[reg] + sH[rl * 66 + c0];
            float v1 = acc1[reg] + sH[rl * 66 + c1];
            float* p0 = &out[(size_t)d * 64 + c0];
            float* p1 = &out[(size_t)d * 64 + c1];
            if (sCnt[rl] > CAP) {      // row shared with ovf fixup -> atomic
                unsafeAtomicAdd(p0, v0);
                unsafeAtomicAdd(p1, v1);
            } else {                   // sole writer -> plain RMW
                *p0 += v0;
                *p1 += v1;
            }
        }
    }
}

extern "C" void kernel_launch(void* const* d_in, const int* in_sizes, int n_in,
                              void* d_out, int out_size, void* d_ws, size_t ws_size,
                              hipStream_t stream) {
    const float* x  = (const float*)d_in[0];
    const float* ef = (const float*)d_in[1];
    const int* nt   = (const int*)d_in[2];
    const int* es   = (const int*)d_in[3];
    const int* ed   = (const int*)d_in[4];
    const int* et   = (const int*)d_in[5];
    const float* W1 = (const float*)d_in[6];
    const float* b1 = (const float*)d_in[7];
    const float* W2 = (const float*)d_in[8];
    const float* b2 = (const float*)d_in[9];
    // d_in[10..13] = W3,b3,W4,b4 dead (score == 1.0)
    const float* W5 = (const float*)d_in[14];
    const float* b5 = (const float*)d_in[15];

    int N = in_sizes[2];
    int M = in_sizes[3];

    char* w = (char*)d_ws;
    size_t off = 0;
    unsigned short* h2b = (unsigned short*)(w + off); off += (size_t)N * 64 * 2;  // 12.8 MB
    off = (off + 255) & ~(size_t)255;
    int2* rec = (int2*)(w + off); off += (size_t)N * CAP * 8;                     // 12.8 MB
    off = (off + 255) & ~(size_t)255;
    int4* ovf = (int4*)(w + off); off += (size_t)OVF_CAP * 16;                    // 0.5 MB
    off = (off + 255) & ~(size_t)255;
    // zero block: [ovfCnt:1 int][pad->64 B][cnt32: N ints]
    int* ovfCnt = (int*)(w + off);
    int* cnt32  = (int*)(w + off + 64);
    size_t zeroBytes = 64 + (size_t)N * 4;

    float* out = (float*)d_out;

    hipMemsetAsync(ovfCnt, 0, zeroBytes, stream);

    int gemmBlocks    = (N + 127) / 128;    // 782
    int scatterBlocks = (M + 1023) / 1024;  // 782
    int gb1 = 2 * max(gemmBlocks, scatterBlocks);
    k1_gemm_scatter<<<gb1, 256, 0, stream>>>(
        x, nt, W1, b1, W2, b2, es, ed, et,
        cnt32, ovfCnt, ovf, rec, out, h2b, N, M);

    int gatherBlocks = (N + 31) / 32;       // 3125
    int ovfBlocks = 32;
    k2_gather_mm<<<gatherBlocks + ovfBlocks, 256, 0, stream>>>(
        ef, rec, cnt32, W5, b5, ovf, ovfCnt, h2b, out,
        N, gatherBlocks, ovfBlocks);
}